// Round 8
// baseline (232.860 us; speedup 1.0000x reference)
//
#include <hip/hip_runtime.h>
#include <math.h>

// Problem constants (N = 1024)
#define M_ROWS  81920            // 1024*8*10 score rows
#define NCOLS   4096
#define KPAD    48               // 45 padded to 48 (3 k-tiles of 16 for 32x32x16)
#define CROUNDS 128              // 4096/32: every wave sweeps ALL columns
#define ITERS   64               // 2 col-rounds per LDS iteration
#define GHALVES 3072             // _Float16 per 32-col group: 6 bufs * 512
#define ITBYTES 12288            // bytes staged per iteration (2 groups)
#define LO_SCALE 4096.0f         // 2^12: keeps f16 residuals out of subnormal range
#define INV_LO   (1.0f / 4096.0f)

typedef _Float16 f16x8  __attribute__((ext_vector_type(8)));
typedef float    f32x16 __attribute__((ext_vector_type(16)));

// ws layout (0.75 MB):
//   Bfrag : _Float16[128 groups][6 bufs][512]   fragment-major
// Fragment-major: for 32-col group g, buffer f (f<3: hi k-tile f; f>=3: lo
// k-tile f-3), the 64 lanes' 16B MFMA B-fragments stored CONTIGUOUSLY at
// lane*16B. LDS staging is a LINEAR byte copy of this layout.
//
// NOTE (rounds 6/7): the global_load_lds variant of this design killed the
// container twice; every other mechanism here has passed before. This
// version stages via registers + ds_write_b128 (T14 async split) instead.

// ---------------------------------------------------------------------------
// Build Bfrag: split H (45 x 4096, [d][n]) into hi/lo f16, emit in
// fragment-major order. Lane mapping within a buffer: lane = half*32 + c,
// holding col (g*32+c), k's [kt*16 + half*8, +8), pad k=45..47 zeroed.
__global__ void build_B_kernel(const float* __restrict__ H,
                               _Float16* __restrict__ Bfrag) {
    const int n = blockIdx.x * 256 + threadIdx.x;     // col [0,4096)
    _Float16 hi[KPAD], lo[KPAD];
    #pragma unroll
    for (int k = 0; k < 45; ++k) {
        const float h = H[k * NCOLS + n];
        const _Float16 h1 = (_Float16)h;
        hi[k] = h1;
        lo[k] = (_Float16)((h - (float)h1) * LO_SCALE);
    }
    #pragma unroll
    for (int k = 45; k < KPAD; ++k) { hi[k] = (_Float16)0.f; lo[k] = (_Float16)0.f; }

    const int g = n >> 5;
    const int c = n & 31;
    _Float16* gbase = Bfrag + (size_t)g * GHALVES;
    #pragma unroll
    for (int f = 0; f < 6; ++f) {
        const int kt = (f < 3) ? f : f - 3;
        const _Float16* src = ((f < 3) ? hi : lo) + kt * 16;
        #pragma unroll
        for (int h = 0; h < 2; ++h) {
            // lane = h*32 + c  ->  halves offset lane*8
            *(f16x8*)(gbase + f * 512 + (h * 32 + c) * 8) =
                *(const f16x8*)(src + h * 8);
        }
    }
}

// ---------------------------------------------------------------------------
// Fused MFMA GEMM + argmax + LUT gather, LDS-staged B (reg-staged copy).
// Block = 256 threads = 4 waves x 32 rows = 128 rows; the block sweeps all
// 4096 cols in 64 double-buffered LDS iterations (2 col-rounds = 12KB each).
// B is read from L2 ONCE PER BLOCK (506 MB total vs 1.97 GB in round 5 --
// the measured L2-stream bottleneck). Argmax fully wave-internal (each wave
// sees every column for its rows): no cross-chunk reduce.
//
// Staging (T14 async split): per iteration each thread (a) issues 3 x 16B
// global loads for iter it+1 into regs, (b) computes 2 col-rounds from
// sB[cur], (c) ds_write_b128 the regs to sB[nxt] (vmcnt wait covered by the
// compute), (d) one barrier. No wave writes a buffer any wave reads within
// the same barrier epoch. Bounds: global max = 63*12288+8192+4080+16 =
// 786432 = sizeof(Bfrag); LDS max = 12288 = sizeof(sB[i]).
//
// REGISTER BUDGET (measured r2-r5): 2nd launch_bounds arg acts like CUDA
// min-blocks/CU; cap = 131072/(threads*arg). (256,4) -> 128 cap; r4/r5
// measured 48 arch VGPRs for this structure; +12 staging regs fits easily.
//
// 32x32 layouts: A[m=lane&31][k=(lane>>5)*8+j]; B[k=(lane>>5)*8+j][n=lane&31];
// C/D: col=lane&31, row=(reg&3)+8*(reg>>2)+4*(lane>>5)   (m74/m101-verified).
__global__ __launch_bounds__(256, 4) void score_argmax_kernel(
        const float* __restrict__ x,   // (1024, 480)
        const float* __restrict__ S,   // (30, 2, 15)
        const float* __restrict__ T,   // (30, 15)
        const _Float16* __restrict__ Bfrag,
        const float* __restrict__ LUT, // (10, 4096, 2)
        float* __restrict__ out) {     // (81920, 2)
    const int tid  = threadIdx.x;
    const int lane = tid & 63;
    const int l31  = lane & 31;
    const int half = lane >> 5;                       // 0 or 1
    const int wid  = tid >> 6;                        // wave id [0,4)
    const int rowbase = blockIdx.x * 128 + wid * 32;  // wave's first row

    __shared__ _Float16 sB[2][2 * GHALVES];           // 2 x 12KB double buffer

    // ---- inline A: afr[kt][j] = y(rowbase + l31, kt*16 + half*8 + j)
    // y = sign(x4·S - T - 1e-4), exactly ±1/0 in f16; zero for k >= 45.
    f16x8 afr[3];
    {
        const int row  = rowbase + l31;
        const int pair = row / 10;
        const int c2   = row - pair * 10;
        const int a    = pair >> 3;
        const int b    = pair & 7;
        const float* xp = x + a * 480 + b * 60;
        #pragma unroll
        for (int kt = 0; kt < 3; ++kt) {
            #pragma unroll
            for (int j = 0; j < 8; ++j) {
                const int k    = kt * 16 + half * 8 + j;     // [0,48)
                const bool pad = (k >= 45);
                const int kcl  = pad ? 0 : k;                // clamp for safe addrs
                const int cc   = kcl / 15;                   // const-divisor magic
                const int kk   = kcl - cc * 15;
                const int c    = c2 * 3 + cc;
                const float x0 = xp[c * 2 + 0];
                const float x1 = xp[c * 2 + 1];
                float v = x0 * S[(c * 2 + 0) * 15 + kk] + x1 * S[(c * 2 + 1) * 15 + kk];
                v = v - T[c * 15 + kk] - 1e-4f;
                const float yv = (v > 0.f) ? 1.f : ((v < 0.f) ? -1.f : 0.f);
                afr[kt][j] = pad ? (_Float16)0.f : (_Float16)yv;
            }
        }
    }

    float best[16];
    int   bidx[16];
    #pragma unroll
    for (int e = 0; e < 16; ++e) { best[e] = -INFINITY; bidx[e] = 0; }

    const char* gB = (const char*)Bfrag;
    char* const lds0 = (char*)&sB[0][0];
    char* const lds1 = (char*)&sB[1][0];
    const size_t toff = (size_t)tid * 16;

    f16x8 st[3];

    // ---- prologue: stage iteration 0 into sB[0] (linear 12KB block copy)
    #pragma unroll
    for (int q = 0; q < 3; ++q)
        st[q] = *(const f16x8*)(gB + (size_t)q * 4096 + toff);
    #pragma unroll
    for (int q = 0; q < 3; ++q)
        *(f16x8*)(lds0 + q * 4096 + toff) = st[q];
    __syncthreads();

    // one iteration body: read LDS 'rd', stage iter 'itn' into LDS 'wr'
#define ITER_BODY(rd, wr, it, itn) do {                                     \
        _Pragma("unroll")                                                   \
        for (int q = 0; q < 3; ++q)                                         \
            st[q] = *(const f16x8*)(gB + (size_t)(itn) * ITBYTES            \
                                       + (size_t)q * 4096 + toff);          \
        _Pragma("unroll")                                                   \
        for (int rr = 0; rr < 2; ++rr) {                                    \
            const _Float16* fb = (const _Float16*)((rd) + rr * 6144)        \
                                 + (size_t)lane * 8;                        \
            f16x8 cb[6];                                                    \
            _Pragma("unroll")                                               \
            for (int f = 0; f < 6; ++f) cb[f] = *(const f16x8*)(fb + f * 512); \
            f32x16 ch = {0.f};                                              \
            f32x16 cl = {0.f};                                              \
            ch = __builtin_amdgcn_mfma_f32_32x32x16_f16(afr[0], cb[0], ch, 0, 0, 0); \
            ch = __builtin_amdgcn_mfma_f32_32x32x16_f16(afr[1], cb[1], ch, 0, 0, 0); \
            ch = __builtin_amdgcn_mfma_f32_32x32x16_f16(afr[2], cb[2], ch, 0, 0, 0); \
            cl = __builtin_amdgcn_mfma_f32_32x32x16_f16(afr[0], cb[3], cl, 0, 0, 0); \
            cl = __builtin_amdgcn_mfma_f32_32x32x16_f16(afr[1], cb[4], cl, 0, 0, 0); \
            cl = __builtin_amdgcn_mfma_f32_32x32x16_f16(afr[2], cb[5], cl, 0, 0, 0); \
            const int mycol = ((it) * 2 + rr) * 32 + l31;                   \
            _Pragma("unroll")                                               \
            for (int e = 0; e < 16; ++e) {                                  \
                const float s = fmaf(cl[e], INV_LO, ch[e]);                 \
                if (s > best[e]) bidx[e] = mycol;  /* cols ascend */        \
                best[e] = fmaxf(best[e], s);                                \
            }                                                               \
        }                                                                   \
        _Pragma("unroll")                                                   \
        for (int q = 0; q < 3; ++q)                                         \
            *(f16x8*)((wr) + q * 4096 + toff) = st[q];                      \
        __syncthreads();                                                    \
    } while (0)

    // x2 unrolled ping-pong: LDS bases are compile-time constants.
    for (int it2 = 0; it2 < ITERS; it2 += 2) {
        ITER_BODY(lds0, lds1, it2,     it2 + 1);              // itn <= 63
        ITER_BODY(lds1, lds0, it2 + 1, (it2 + 2) & (ITERS - 1)); // wrap: in ws
    }
#undef ITER_BODY

    // Cross-lane argmax over the 32 cols held by l31=0..31 (same half).
    // Tie -> smaller index (jnp.argmax first-index semantics).
    #pragma unroll
    for (int m = 1; m < 32; m <<= 1) {
        #pragma unroll
        for (int e = 0; e < 16; ++e) {
            const float ov = __shfl_xor(best[e], m, 64);
            const int   oi = __shfl_xor(bidx[e], m, 64);
            if (ov > best[e] || (ov == best[e] && oi < bidx[e])) {
                best[e] = ov; bidx[e] = oi;
            }
        }
    }

    // Each wave saw ALL 4096 cols: gather LUT + write directly, no reduce.
    if (l31 == 0) {   // lanes 0 and 32 write their half's rows
        #pragma unroll
        for (int e = 0; e < 16; ++e) {
            const int row = rowbase + (e & 3) + 8 * (e >> 2) + 4 * half;
            const int pair = row / 10;
            const int c2   = row - pair * 10;
            const float* l = LUT + ((size_t)c2 * NCOLS + bidx[e]) * 2;
            out[row * 2 + 0] = l[0];
            out[row * 2 + 1] = l[1];
        }
    }
}

// ---------------------------------------------------------------------------
extern "C" void kernel_launch(void* const* d_in, const int* in_sizes, int n_in,
                              void* d_out, int out_size, void* d_ws, size_t ws_size,
                              hipStream_t stream) {
    const float* x   = (const float*)d_in[0];  // 1024*480
    const float* S   = (const float*)d_in[1];  // 30*2*15
    const float* T   = (const float*)d_in[2];  // 30*15
    const float* H   = (const float*)d_in[3];  // 45*4096
    const float* LUT = (const float*)d_in[4];  // 10*4096*2
    float* out = (float*)d_out;                // 1024*8*10*2

    _Float16* Bfrag = (_Float16*)d_ws;         // 128 groups * 3072 halves

    build_B_kernel<<<16, 256, 0, stream>>>(H, Bfrag);
    // 640 blocks x 4 waves x 32 rows = 81920 rows; each block sweeps all
    // 4096 cols from a 24KB LDS double buffer. 4 blocks/CU (128-VGPR cap).
    score_argmax_kernel<<<640, 256, 0, stream>>>(x, S, T, Bfrag, LUT, out);
}

// Round 9
// 203.472 us; speedup vs baseline: 1.1444x; 1.1444x over previous
//
#include <hip/hip_runtime.h>
#include <math.h>

// Problem constants (N = 1024)
#define M_ROWS  81920            // 1024*8*10 score rows
#define NCOLS   4096
#define KPAD    48               // 45 padded to 48 (3 k-tiles of 16 for 32x32x16)
#define CROUNDS 128              // 4096/32: every wave sweeps ALL columns
#define ITERS   64               // 2 col-rounds per LDS iteration
#define GHALVES 3072             // _Float16 per 32-col group: 6 bufs * 512
#define ITBYTES 12288            // bytes staged per iteration (2 groups)
#define LO_SCALE 4096.0f         // 2^12: keeps f16 residuals out of subnormal range
#define INV_LO   (1.0f / 4096.0f)

typedef _Float16 f16x8  __attribute__((ext_vector_type(8)));
typedef float    f32x16 __attribute__((ext_vector_type(16)));

// ws layout (0.75 MB):
//   Bfrag : _Float16[128 groups][6 bufs][512]   fragment-major
// Fragment-major: for 32-col group g, buffer f (f<3: hi k-tile f; f>=3: lo
// k-tile f-3), the 64 lanes' 16B MFMA B-fragments stored CONTIGUOUSLY at
// lane*16B. LDS staging is a LINEAR byte copy of this layout.
//
// LAUNCH-BOUNDS LAW (measured r2,r3,r8): arch-VGPR cap = 256/arg2,
// INDEPENDENT of block size. (512,4)&(256,4) -> 64 (both spilled);
// (512,2)&(256,2) -> 128. This kernel needs ~76-96 -> use arg2=2.

// ---------------------------------------------------------------------------
// Build Bfrag: split H (45 x 4096, [d][n]) into hi/lo f16, emit in
// fragment-major order. Lane mapping within a buffer: lane = half*32 + c,
// holding col (g*32+c), k's [kt*16 + half*8, +8), pad k=45..47 zeroed.
__global__ void build_B_kernel(const float* __restrict__ H,
                               _Float16* __restrict__ Bfrag) {
    const int n = blockIdx.x * 256 + threadIdx.x;     // col [0,4096)
    _Float16 hi[KPAD], lo[KPAD];
    #pragma unroll
    for (int k = 0; k < 45; ++k) {
        const float h = H[k * NCOLS + n];
        const _Float16 h1 = (_Float16)h;
        hi[k] = h1;
        lo[k] = (_Float16)((h - (float)h1) * LO_SCALE);
    }
    #pragma unroll
    for (int k = 45; k < KPAD; ++k) { hi[k] = (_Float16)0.f; lo[k] = (_Float16)0.f; }

    const int g = n >> 5;
    const int c = n & 31;
    _Float16* gbase = Bfrag + (size_t)g * GHALVES;
    #pragma unroll
    for (int f = 0; f < 6; ++f) {
        const int kt = (f < 3) ? f : f - 3;
        const _Float16* src = ((f < 3) ? hi : lo) + kt * 16;
        #pragma unroll
        for (int h = 0; h < 2; ++h) {
            // lane = h*32 + c  ->  halves offset lane*8
            *(f16x8*)(gbase + f * 512 + (h * 32 + c) * 8) =
                *(const f16x8*)(src + h * 8);
        }
    }
}

// ---------------------------------------------------------------------------
// Fused MFMA GEMM + argmax + LUT gather, LDS-staged B (reg-staged copy).
// Block = 320 threads = 5 waves x 32 rows = 160 rows; 512 blocks = EXACTLY
// 2 blocks/CU, perfectly balanced (640x4-wave blocks had a 2-vs-3 blocks/CU
// 17% critical-path imbalance). Block sweeps all 4096 cols in 64
// double-buffered LDS iterations (2 col-rounds = 12KB each). B read from L2
// ONCE PER BLOCK: 384 MB total vs 1.97 GB in round 5 (the measured
// L2-stream bottleneck). Argmax fully wave-internal: no cross-chunk reduce.
//
// Staging (T14 async split): threads 0..255 (waves 0-3; wave-uniform
// predicate) each (a) issue 3 x 16B global loads for iter it+1 into regs,
// (b) all 5 waves compute 2 col-rounds from sB[cur], (c) stagers
// ds_write_b128 the regs to sB[nxt], (d) one barrier. No wave writes a
// buffer any wave reads in the same barrier epoch. Bounds: global max =
// 63*12288+8192+4080+16 = 786432 = sizeof(Bfrag); LDS max = 12288 =
// sizeof(sB[i]).
//
// 32x32 layouts: A[m=lane&31][k=(lane>>5)*8+j]; B[k=(lane>>5)*8+j][n=lane&31];
// C/D: col=lane&31, row=(reg&3)+8*(reg>>2)+4*(lane>>5)   (m74/m101-verified).
__global__ __launch_bounds__(320, 2) void score_argmax_kernel(
        const float* __restrict__ x,   // (1024, 480)
        const float* __restrict__ S,   // (30, 2, 15)
        const float* __restrict__ T,   // (30, 15)
        const _Float16* __restrict__ Bfrag,
        const float* __restrict__ LUT, // (10, 4096, 2)
        float* __restrict__ out) {     // (81920, 2)
    const int tid  = threadIdx.x;
    const int lane = tid & 63;
    const int l31  = lane & 31;
    const int half = lane >> 5;                       // 0 or 1
    const int wid  = tid >> 6;                        // wave id [0,5)
    const int rowbase = blockIdx.x * 160 + wid * 32;  // wave's first row
    const bool stager = (tid < 256);                  // wave-uniform

    __shared__ _Float16 sB[2][2 * GHALVES];           // 2 x 12KB double buffer

    // ---- inline A: afr[kt][j] = y(rowbase + l31, kt*16 + half*8 + j)
    // y = sign(x4·S - T - 1e-4), exactly ±1/0 in f16; zero for k >= 45.
    f16x8 afr[3];
    {
        const int row  = rowbase + l31;
        const int pair = row / 10;
        const int c2   = row - pair * 10;
        const int a    = pair >> 3;
        const int b    = pair & 7;
        const float* xp = x + a * 480 + b * 60;
        #pragma unroll
        for (int kt = 0; kt < 3; ++kt) {
            #pragma unroll
            for (int j = 0; j < 8; ++j) {
                const int k    = kt * 16 + half * 8 + j;     // [0,48)
                const bool pad = (k >= 45);
                const int kcl  = pad ? 0 : k;                // clamp for safe addrs
                const int cc   = kcl / 15;                   // const-divisor magic
                const int kk   = kcl - cc * 15;
                const int c    = c2 * 3 + cc;
                const float x0 = xp[c * 2 + 0];
                const float x1 = xp[c * 2 + 1];
                float v = x0 * S[(c * 2 + 0) * 15 + kk] + x1 * S[(c * 2 + 1) * 15 + kk];
                v = v - T[c * 15 + kk] - 1e-4f;
                const float yv = (v > 0.f) ? 1.f : ((v < 0.f) ? -1.f : 0.f);
                afr[kt][j] = pad ? (_Float16)0.f : (_Float16)yv;
            }
        }
    }

    float best[16];
    int   bidx[16];
    #pragma unroll
    for (int e = 0; e < 16; ++e) { best[e] = -INFINITY; bidx[e] = 0; }

    const char* gB = (const char*)Bfrag;
    char* const lds0 = (char*)&sB[0][0];
    char* const lds1 = (char*)&sB[1][0];
    const size_t toff = (size_t)tid * 16;             // stagers: [0, 4096)

    f16x8 st[3];

    // ---- prologue: stage iteration 0 into sB[0] (linear 12KB block copy)
    if (stager) {
        #pragma unroll
        for (int q = 0; q < 3; ++q)
            st[q] = *(const f16x8*)(gB + (size_t)q * 4096 + toff);
        #pragma unroll
        for (int q = 0; q < 3; ++q)
            *(f16x8*)(lds0 + q * 4096 + toff) = st[q];
    }
    __syncthreads();

    // one iteration body: read LDS 'rd', stage iter 'itn' into LDS 'wr'
#define ITER_BODY(rd, wr, it, itn) do {                                     \
        if (stager) {                                                       \
            _Pragma("unroll")                                               \
            for (int q = 0; q < 3; ++q)                                     \
                st[q] = *(const f16x8*)(gB + (size_t)(itn) * ITBYTES        \
                                           + (size_t)q * 4096 + toff);      \
        }                                                                   \
        _Pragma("unroll")                                                   \
        for (int rr = 0; rr < 2; ++rr) {                                    \
            const _Float16* fb = (const _Float16*)((rd) + rr * 6144)        \
                                 + (size_t)lane * 8;                        \
            f16x8 cb[6];                                                    \
            _Pragma("unroll")                                               \
            for (int f = 0; f < 6; ++f) cb[f] = *(const f16x8*)(fb + f * 512); \
            f32x16 ch = {0.f};                                              \
            f32x16 cl = {0.f};                                              \
            ch = __builtin_amdgcn_mfma_f32_32x32x16_f16(afr[0], cb[0], ch, 0, 0, 0); \
            ch = __builtin_amdgcn_mfma_f32_32x32x16_f16(afr[1], cb[1], ch, 0, 0, 0); \
            ch = __builtin_amdgcn_mfma_f32_32x32x16_f16(afr[2], cb[2], ch, 0, 0, 0); \
            cl = __builtin_amdgcn_mfma_f32_32x32x16_f16(afr[0], cb[3], cl, 0, 0, 0); \
            cl = __builtin_amdgcn_mfma_f32_32x32x16_f16(afr[1], cb[4], cl, 0, 0, 0); \
            cl = __builtin_amdgcn_mfma_f32_32x32x16_f16(afr[2], cb[5], cl, 0, 0, 0); \
            const int mycol = ((it) * 2 + rr) * 32 + l31;                   \
            _Pragma("unroll")                                               \
            for (int e = 0; e < 16; ++e) {                                  \
                const float s = fmaf(cl[e], INV_LO, ch[e]);                 \
                if (s > best[e]) bidx[e] = mycol;  /* cols ascend */        \
                best[e] = fmaxf(best[e], s);                                \
            }                                                               \
        }                                                                   \
        if (stager) {                                                       \
            _Pragma("unroll")                                               \
            for (int q = 0; q < 3; ++q)                                     \
                *(f16x8*)((wr) + q * 4096 + toff) = st[q];                  \
        }                                                                   \
        __syncthreads();                                                    \
    } while (0)

    // x2 unrolled ping-pong: LDS bases are compile-time constants.
    for (int it2 = 0; it2 < ITERS; it2 += 2) {
        ITER_BODY(lds0, lds1, it2,     it2 + 1);                 // itn <= 63
        ITER_BODY(lds1, lds0, it2 + 1, (it2 + 2) & (ITERS - 1)); // wrap: in ws
    }
#undef ITER_BODY

    // Cross-lane argmax over the 32 cols held by l31=0..31 (same half).
    // Tie -> smaller index (jnp.argmax first-index semantics).
    #pragma unroll
    for (int m = 1; m < 32; m <<= 1) {
        #pragma unroll
        for (int e = 0; e < 16; ++e) {
            const float ov = __shfl_xor(best[e], m, 64);
            const int   oi = __shfl_xor(bidx[e], m, 64);
            if (ov > best[e] || (ov == best[e] && oi < bidx[e])) {
                best[e] = ov; bidx[e] = oi;
            }
        }
    }

    // Each wave saw ALL 4096 cols: gather LUT + write directly, no reduce.
    if (l31 == 0) {   // lanes 0 and 32 write their half's rows
        #pragma unroll
        for (int e = 0; e < 16; ++e) {
            const int row = rowbase + (e & 3) + 8 * (e >> 2) + 4 * half;
            const int pair = row / 10;
            const int c2   = row - pair * 10;
            const float* l = LUT + ((size_t)c2 * NCOLS + bidx[e]) * 2;
            out[row * 2 + 0] = l[0];
            out[row * 2 + 1] = l[1];
        }
    }
}

// ---------------------------------------------------------------------------
extern "C" void kernel_launch(void* const* d_in, const int* in_sizes, int n_in,
                              void* d_out, int out_size, void* d_ws, size_t ws_size,
                              hipStream_t stream) {
    const float* x   = (const float*)d_in[0];  // 1024*480
    const float* S   = (const float*)d_in[1];  // 30*2*15
    const float* T   = (const float*)d_in[2];  // 30*15
    const float* H   = (const float*)d_in[3];  // 45*4096
    const float* LUT = (const float*)d_in[4];  // 10*4096*2
    float* out = (float*)d_out;                // 1024*8*10*2

    _Float16* Bfrag = (_Float16*)d_ws;         // 128 groups * 3072 halves

    build_B_kernel<<<16, 256, 0, stream>>>(H, Bfrag);
    // 512 blocks x 5 waves x 32 rows = 81920 rows; exactly 2 blocks/CU,
    // each block sweeps all 4096 cols from a 24KB LDS double buffer.
    score_argmax_kernel<<<512, 320, 0, stream>>>(x, S, T, Bfrag, LUT, out);
}

// Round 10
// 191.001 us; speedup vs baseline: 1.2192x; 1.0653x over previous
//
#include <hip/hip_runtime.h>
#include <math.h>

// Problem constants (N = 1024)
#define M_ROWS  81920            // 1024*8*10 score rows
#define NCOLS   4096
#define KPAD    48               // 45 padded to 48 (3 k-tiles of 16 for 32x32x16)
#define NCHUNK  4
#define CHUNKC  (NCOLS / NCHUNK) // 1024 cols per chunk
#define CROUNDS (CHUNKC / 32)    // 32 col-rounds of 32 cols
#define GHALVES 3072             // _Float16 per 32-col group: 6 bufs * 512
#define LO_SCALE 4096.0f         // 2^12: keeps f16 residuals out of subnormal range
#define INV_LO   (1.0f / 4096.0f)

typedef _Float16 f16x8  __attribute__((ext_vector_type(8)));
typedef float    f32x16 __attribute__((ext_vector_type(16)));

// ws layout (~3.4 MB). ORDER MATTERS: the pipelined GEMM overreads up to one
// 32-col group (6 KB) past Bfrag on its final prefetch (chunk 3) — values
// unused, memory must be valid (lands in pbest).
//   Bfrag: _Float16[128 groups][6 bufs][512]  fragment-major   0.75 MB
//   pbest: float[81920 * 4]                                    1.31 MB
//   pidx : int  [81920 * 4]                                    1.31 MB
//
// Fragment-major (measured r5: 3x less L1 pipe work vs [col][k]): for 32-col
// group g, buffer f (f<3: hi k-tile f; f>=3: lo k-tile f-3), the 64 lanes'
// 16B MFMA B-fragments are CONTIGUOUS at lane*16B -> 1KB coalesced per load.
//
// STRUCTURE NOTE (measured r0-r9): this is round-0's proven kernel (112
// VGPR, no spill at (256,2); 64-row waves halve the B load stream vs
// 32-row) with ONLY the B layout swapped to fragment-major. LDS-staged
// variants (r8/r9) lost to barrier lockstep; fused-tail variants (r3)
// spilled. Launch-bounds law: arch-VGPR cap = 256/arg2 (r2,r3,r8).

// ---------------------------------------------------------------------------
// Build Bfrag: split H (45 x 4096, [d][n]) into hi/lo f16, emit in
// fragment-major order. Lane mapping within a buffer: lane = half*32 + c,
// holding col (g*32+c), k's [kt*16 + half*8, +8), pad k=45..47 zeroed.
__global__ void build_B_kernel(const float* __restrict__ H,
                               _Float16* __restrict__ Bfrag) {
    const int n = blockIdx.x * 256 + threadIdx.x;     // col [0,4096)
    _Float16 hi[KPAD], lo[KPAD];
    #pragma unroll
    for (int k = 0; k < 45; ++k) {
        const float h = H[k * NCOLS + n];
        const _Float16 h1 = (_Float16)h;
        hi[k] = h1;
        lo[k] = (_Float16)((h - (float)h1) * LO_SCALE);
    }
    #pragma unroll
    for (int k = 45; k < KPAD; ++k) { hi[k] = (_Float16)0.f; lo[k] = (_Float16)0.f; }

    const int g = n >> 5;
    const int c = n & 31;
    _Float16* gbase = Bfrag + (size_t)g * GHALVES;
    #pragma unroll
    for (int f = 0; f < 6; ++f) {
        const int kt = (f < 3) ? f : f - 3;
        const _Float16* src = ((f < 3) ? hi : lo) + kt * 16;
        #pragma unroll
        for (int h = 0; h < 2; ++h) {
            // lane = h*32 + c  ->  halves offset lane*8
            *(f16x8*)(gbase + f * 512 + (h * 32 + c) * 8) =
                *(const f16x8*)(src + h * 8);
        }
    }
}

// ---------------------------------------------------------------------------
// MFMA GEMM + fused argmax, 32x32x16 shape, inline A computation.
// wave = 64 rows (2 row-tiles of 32) x 1024-col chunk, 32-col rounds,
// branch-free double-buffered B prefetch. Block's 4 waves share a chunk.
// 32x32 layouts: A[m=lane&31][k=(lane>>5)*8+j]; B[k=(lane>>5)*8+j][n=lane&31];
// C/D: col=lane&31, row=(reg&3)+8*(reg>>2)+4*(lane>>5)   (m74/m101-verified).
__global__ __launch_bounds__(256, 2) void score_argmax_kernel(
        const float* __restrict__ x,   // (1024, 480)
        const float* __restrict__ S,   // (30, 2, 15)
        const float* __restrict__ T,   // (30, 15)
        const _Float16* __restrict__ Bfrag,
        float* __restrict__ pbest,
        int*   __restrict__ pidx) {
    const int tid  = threadIdx.x;
    const int lane = tid & 63;
    const int l31  = lane & 31;
    const int half = lane >> 5;                       // 0 or 1
    const int chunk = blockIdx.x / 320;               // block-uniform
    const int rg    = (blockIdx.x - chunk * 320) * 4 + (tid >> 6);  // [0,1280)
    const int rowbase = rg * 64;

    // ---- inline A: afr[rt][kt][j] = y(rowbase + rt*32 + l31, kt*16 + half*8 + j)
    // y = sign(x4·S - T - 1e-4), exactly ±1/0 in f16; zero for k >= 45.
    f16x8 afr[2][3];
    #pragma unroll
    for (int rt = 0; rt < 2; ++rt) {
        const int row  = rowbase + rt * 32 + l31;
        const int pair = row / 10;
        const int c2   = row - pair * 10;
        const int a    = pair >> 3;
        const int b    = pair & 7;
        const float* xp = x + a * 480 + b * 60;
        #pragma unroll
        for (int kt = 0; kt < 3; ++kt) {
            #pragma unroll
            for (int j = 0; j < 8; ++j) {
                const int k    = kt * 16 + half * 8 + j;     // [0,48)
                const bool pad = (k >= 45);
                const int kcl  = pad ? 0 : k;                // clamp for safe addrs
                const int cc   = kcl / 15;                   // const-divisor magic
                const int kk   = kcl - cc * 15;
                const int c    = c2 * 3 + cc;
                const float x0 = xp[c * 2 + 0];
                const float x1 = xp[c * 2 + 1];
                float v = x0 * S[(c * 2 + 0) * 15 + kk] + x1 * S[(c * 2 + 1) * 15 + kk];
                v = v - T[c * 15 + kk] - 1e-4f;
                const float yv = (v > 0.f) ? 1.f : ((v < 0.f) ? -1.f : 0.f);
                afr[rt][kt][j] = pad ? (_Float16)0.f : (_Float16)yv;
            }
        }
    }

    float best[2][16];
    int   bidx[2][16];
    #pragma unroll
    for (int rt = 0; rt < 2; ++rt)
        #pragma unroll
        for (int e = 0; e < 16; ++e) { best[rt][e] = -INFINITY; bidx[rt][e] = 0; }

    const int colbase0 = chunk * CHUNKC;
    // fragment-major per-lane base for this chunk (groups chunk*32 ..)
    const _Float16* fbase = Bfrag + (size_t)(chunk * 32) * GHALVES
                                  + (size_t)lane * 8;

    // double-buffered B fragments (hi/lo x 3 k-tiles); all loads unconditional.
    f16x8 cb[6], nb[6];
    #pragma unroll
    for (int f = 0; f < 6; ++f) cb[f] = *(const f16x8*)(fbase + f * 512);

    for (int ct = 0; ct < CROUNDS; ++ct) {
        // prefetch round ct+1 (final iter overreads 6KB into pbest: valid)
        {
            const _Float16* np = fbase + (size_t)(ct + 1) * GHALVES;
            #pragma unroll
            for (int f = 0; f < 6; ++f) nb[f] = *(const f16x8*)(np + f * 512);
        }
        const int mycol = colbase0 + ct * 32 + l31;   // same col for all 32 scores
        #pragma unroll
        for (int rt = 0; rt < 2; ++rt) {
            f32x16 ch = {0.f};
            f32x16 cl = {0.f};
            ch = __builtin_amdgcn_mfma_f32_32x32x16_f16(afr[rt][0], cb[0], ch, 0, 0, 0);
            ch = __builtin_amdgcn_mfma_f32_32x32x16_f16(afr[rt][1], cb[1], ch, 0, 0, 0);
            ch = __builtin_amdgcn_mfma_f32_32x32x16_f16(afr[rt][2], cb[2], ch, 0, 0, 0);
            cl = __builtin_amdgcn_mfma_f32_32x32x16_f16(afr[rt][0], cb[3], cl, 0, 0, 0);
            cl = __builtin_amdgcn_mfma_f32_32x32x16_f16(afr[rt][1], cb[4], cl, 0, 0, 0);
            cl = __builtin_amdgcn_mfma_f32_32x32x16_f16(afr[rt][2], cb[5], cl, 0, 0, 0);
            #pragma unroll
            for (int e = 0; e < 16; ++e) {
                const float s = fmaf(cl[e], INV_LO, ch[e]);
                if (s > best[rt][e]) bidx[rt][e] = mycol;   // cols ascend: > keeps first
                best[rt][e] = fmaxf(best[rt][e], s);
            }
        }
        #pragma unroll
        for (int q = 0; q < 6; ++q) cb[q] = nb[q];
    }

    // Cross-lane argmax over the 32 cols held by l31=0..31 (same half).
    // Tie -> smaller index (jnp.argmax first-index semantics).
    #pragma unroll
    for (int m = 1; m < 32; m <<= 1) {
        #pragma unroll
        for (int rt = 0; rt < 2; ++rt)
            #pragma unroll
            for (int e = 0; e < 16; ++e) {
                const float ov = __shfl_xor(best[rt][e], m, 64);
                const int   oi = __shfl_xor(bidx[rt][e], m, 64);
                if (ov > best[rt][e] ||
                    (ov == best[rt][e] && oi < bidx[rt][e])) {
                    best[rt][e] = ov; bidx[rt][e] = oi;
                }
            }
    }

    if (l31 == 0) {   // lanes 0 and 32 write their half's rows
        #pragma unroll
        for (int rt = 0; rt < 2; ++rt)
            #pragma unroll
            for (int e = 0; e < 16; ++e) {
                const int row = rowbase + rt * 32 + (e & 3) + 8 * (e >> 2) + 4 * half;
                pbest[(size_t)row * NCHUNK + chunk] = best[rt][e];
                pidx [(size_t)row * NCHUNK + chunk] = bidx[rt][e];
            }
    }
}

// ---------------------------------------------------------------------------
// Fold the 4 chunk partials (ascending chunk + strict > == global first-index
// argmax), gather LUT, write out (1024,8,10,2).
__global__ void reduce_lut_kernel(const float* __restrict__ pbest,
                                  const int*   __restrict__ pidx,
                                  const float* __restrict__ LUT,  // (10,4096,2)
                                  float* __restrict__ out) {
    const int row = blockIdx.x * blockDim.x + threadIdx.x;
    if (row >= M_ROWS) return;
    float best = -INFINITY;
    int   bi   = 0;
    #pragma unroll
    for (int ch = 0; ch < NCHUNK; ++ch) {
        const float bv = pbest[(size_t)row * NCHUNK + ch];
        const int   ix = pidx [(size_t)row * NCHUNK + ch];
        if (bv > best) { best = bv; bi = ix; }
    }
    const int pair = row / 10;
    const int c2   = row - pair * 10;
    const float* l = LUT + ((size_t)c2 * NCOLS + bi) * 2;
    out[row * 2 + 0] = l[0];
    out[row * 2 + 1] = l[1];
}

// ---------------------------------------------------------------------------
extern "C" void kernel_launch(void* const* d_in, const int* in_sizes, int n_in,
                              void* d_out, int out_size, void* d_ws, size_t ws_size,
                              hipStream_t stream) {
    const float* x   = (const float*)d_in[0];  // 1024*480
    const float* S   = (const float*)d_in[1];  // 30*2*15
    const float* T   = (const float*)d_in[2];  // 30*15
    const float* H   = (const float*)d_in[3];  // 45*4096
    const float* LUT = (const float*)d_in[4];  // 10*4096*2
    float* out = (float*)d_out;                // 1024*8*10*2

    _Float16* Bfrag = (_Float16*)d_ws;                        // 128*3072 halves
    float*  pbest = (float*)(Bfrag + (size_t)128 * GHALVES);  // 81920*4
    int*    pidx  = (int*)(pbest + (size_t)M_ROWS * NCHUNK);  // 81920*4

    build_B_kernel<<<16, 256, 0, stream>>>(H, Bfrag);
    // 5120 waves = 1280 row-groups x 4 chunks; 4 waves/block, chunk-uniform
    score_argmax_kernel<<<1280, 256, 0, stream>>>(x, S, T, Bfrag, pbest, pidx);
    reduce_lut_kernel<<<M_ROWS / 256, 256, 0, stream>>>(pbest, pidx, LUT, out);
}